// Round 1
// baseline (388.304 us; speedup 1.0000x reference)
//
#include <hip/hip_runtime.h>

#define N_NODES 32000
#define NPG     1000
#define BSZ     32
#define NEDGE   512000
#define H       128
#define NL      3
#define NR      8
#define NW      1152    // 8*128 rel cols + 128 self cols
#define NBIN2   262144  // 32768 dst bins x 8 contention-splitting sub-bins

typedef __attribute__((ext_vector_type(8))) short short8;
typedef __attribute__((ext_vector_type(4))) float float4v;

__device__ __forceinline__ float bf2f(unsigned short u) {
  union { unsigned int i; float f; } v;
  v.i = ((unsigned int)u) << 16;
  return v.f;
}
__device__ __forceinline__ unsigned short f2bf(float f) {
  union { float f; unsigned int i; } v;
  v.f = f;
  unsigned int x = v.i;
  return (unsigned short)((x + 0x7FFFu + ((x >> 16) & 1u)) >> 16);  // RNE
}

// direct global->LDS DMA, 16B per lane (writes wave-uniform base + lane*16)
__device__ __forceinline__ void gl_lds16(const void* g, void* l) {
  __builtin_amdgcn_global_load_lds((__attribute__((address_space(1))) void*)g,
                                   (__attribute__((address_space(3))) void*)l,
                                   16, 0, 0);
}

// ---------------- fused prep: cvtX | cvtB | per-(dst,sub) count | graph hist ----------
__global__ __launch_bounds__(256) void k_prep(
    const float* __restrict__ x, const float* __restrict__ W_rel,
    const float* __restrict__ W_self, const int* __restrict__ dst,
    const int* __restrict__ graph_id,
    unsigned short* __restrict__ hb, unsigned short* __restrict__ Bt,
    int* __restrict__ cnt, int* __restrict__ gcount)
{
  const int b = blockIdx.x, t = threadIdx.x;
  if (b < 4000) {                       // x fp32 -> h0 bf16
    const size_t i = ((size_t)b * 256 + t) * 4;
    float4 v = *(const float4*)(x + i);
    ushort4 u = { f2bf(v.x), f2bf(v.y), f2bf(v.z), f2bf(v.w) };
    *(ushort4*)(hb + i) = u;
  } else if (b < 5728) {                // weights -> Bt9[l][n=0..1151][k] (transposed)
    const int g = (b - 4000) * 256 + t;  // 0..442367
    const int k = g & 127;
    const int n = (g >> 7) % NW;
    const int l = g / (NW * H);
    float v = (n < 1024) ? W_rel[(((size_t)l * NR + (n >> 7)) * H + k) * H + (n & 127)]
                         : W_self[((size_t)l * H + k) * H + (n - 1024)];
    Bt[(size_t)l * (NW * H) + (size_t)n * H + k] = f2bf(v);
  } else if (b < 7728) {                // per-(dst,sub) edge counts, 8-way de-contended
    const int bb = b - 5728;            // 0..1999
    const int e = bb * 256 + t;
    atomicAdd(&cnt[dst[e] * 8 + (bb & 7)], 1);
  } else {                              // graph histogram (125 blocks)
    __shared__ int hist[BSZ];
    if (t < BSZ) hist[t] = 0;
    __syncthreads();
    const int n = (b - 7728) * 256 + t;
    if (n < N_NODES) atomicAdd(&hist[graph_id[n]], 1);
    __syncthreads();
    if (t < BSZ) { int v = hist[t]; if (v) atomicAdd(&gcount[t], v); }
  }
}

// ---------------- 2-phase exclusive scan over NBIN2 bins (scanB folded into scanC) ----
__global__ __launch_bounds__(256) void k_scanA(const int* __restrict__ cnt,
                                               int* __restrict__ bsum) {
  __shared__ int red[256];
  const int t = threadIdx.x;
  int4 v = *(const int4*)(cnt + blockIdx.x * 1024 + t * 4);
  red[t] = v.x + v.y + v.z + v.w;
  __syncthreads();
  for (int off = 128; off > 0; off >>= 1) {
    if (t < off) red[t] += red[t + off];
    __syncthreads();
  }
  if (t == 0) bsum[blockIdx.x] = red[0];
}

__global__ __launch_bounds__(256) void k_scanC(const int* __restrict__ cnt,
                                               const int* __restrict__ bsum,
                                               int* __restrict__ row_ptr2,
                                               int* __restrict__ cursor) {
  __shared__ int ts[256], bsx[256];
  const int t = threadIdx.x;
  const int base = blockIdx.x * 1024 + t * 4;
  int4 v = *(const int4*)(cnt + base);
  const int s = v.x + v.y + v.z + v.w;
  ts[t]  = s;
  bsx[t] = bsum[t];
  __syncthreads();
  for (int off = 1; off < 256; off <<= 1) {   // inclusive Hillis-Steele, both arrays
    int a = (t >= off) ? ts[t - off]  : 0;
    int c = (t >= off) ? bsx[t - off] : 0;
    __syncthreads();
    ts[t] += a; bsx[t] += c;
    __syncthreads();
  }
  const int boff = (blockIdx.x == 0) ? 0 : bsx[blockIdx.x - 1];
  int ex = ts[t] - s + boff;
  int4 w = { ex, ex + v.x, ex + v.x + v.y, ex + v.x + v.y + v.z };
  *(int4*)(row_ptr2 + base) = w;
  *(int4*)(cursor + base) = w;
}

// ---------------- fill: edge_off[p] = src*1152 + etype*128, grouped by (dst,sub) ----
__global__ void k_fill(const int* __restrict__ src, const int* __restrict__ dst,
                       const int* __restrict__ etype, int* __restrict__ cursor,
                       int* __restrict__ edge_off) {
  int e = blockIdx.x * blockDim.x + threadIdx.x;
  if (e < NEDGE) {
    int p = atomicAdd(&cursor[dst[e] * 8 + (blockIdx.x & 7)], 1);
    edge_off[p] = src[e] * NW + etype[e] * H;
  }
}

// ---------------- GEMM9: G = h @ [Wrel(8) | Wself]  (M=32000, K=128, N=1152) --------
// v2: global_load_lds width-16 staging, linear LDS + pre-swizzled source,
//     XOR-swizzled (chunk ^ row&7) reads; same swizzle on epilogue repack.
__global__ __launch_bounds__(256) void k_gemm9(
    const unsigned short* __restrict__ Ah,   // [32000,128] bf16
    const unsigned short* __restrict__ Bt,   // [1152,128]  bf16
    unsigned short* __restrict__ G)          // [32000,1152] bf16
{
  __shared__ __align__(16) unsigned short lds_a[128 * 128];
  __shared__ __align__(16) unsigned short lds_b[128 * 128];
  const int tid  = threadIdx.x;
  const int wave = tid >> 6, lane = tid & 63;
  const int l15 = lane & 15, quad = lane >> 4;
  const int m0 = blockIdx.x * 128;
  const int n0 = blockIdx.y * 128;
  const int mb = (wave & 1) * 64;
  const int nb = (wave >> 1) * 64;

  // stage: 2048 16B-chunks per array; LDS dest linear, global source chunk-swizzled
  #pragma unroll
  for (int i = 0; i < 8; ++i) {
    const int g  = (i * 4 + wave) * 64 + lane;   // 16B chunk id 0..2047
    const int m  = g >> 4;                       // row 0..127
    const int cr = g & 15;                       // chunk-in-row (dest)
    const int cs = cr ^ (m & 7);                 // chunk-in-row (src, pre-swizzled)
    gl_lds16(Ah + (size_t)(m0 + m) * H + cs * 8, lds_a + (size_t)g * 8);
    gl_lds16(Bt + (size_t)(n0 + m) * H + cs * 8, lds_b + (size_t)g * 8);
  }
  __syncthreads();   // compiler drains vmcnt(0) before s_barrier

  float4v acc[4][4];
  #pragma unroll
  for (int i = 0; i < 4; ++i)
    #pragma unroll
    for (int j = 0; j < 4; ++j) acc[i][j] = (float4v){0.f, 0.f, 0.f, 0.f};

  #pragma unroll
  for (int ks = 0; ks < 4; ++ks) {
    const int cr = ks * 4 + quad;                // 16B chunk index within row
    short8 afr[4], bfr[4];
    #pragma unroll
    for (int i = 0; i < 4; ++i) {
      const int row = mb + i * 16 + l15;
      afr[i] = *(const short8*)(lds_a + row * H + ((cr ^ (row & 7)) * 8));
    }
    #pragma unroll
    for (int j = 0; j < 4; ++j) {
      const int row = nb + j * 16 + l15;
      bfr[j] = *(const short8*)(lds_b + row * H + ((cr ^ (row & 7)) * 8));
    }
    #pragma unroll
    for (int i = 0; i < 4; ++i)
      #pragma unroll
      for (int j = 0; j < 4; ++j)
        acc[i][j] = __builtin_amdgcn_mfma_f32_16x16x32_bf16(afr[i], bfr[j], acc[i][j], 0, 0, 0);
  }

  // repack -> coalesced uint4 stores. D: row=quad*4+r, col=l15. Same XOR both sides.
  __syncthreads();
  #pragma unroll
  for (int i = 0; i < 4; ++i)
    #pragma unroll
    for (int j = 0; j < 4; ++j)
      #pragma unroll
      for (int r = 0; r < 4; ++r) {
        const int row = mb + i * 16 + quad * 4 + r;
        const int col = nb + j * 16 + l15;
        lds_a[row * H + ((((col >> 3) ^ (row & 7)) << 3) | (col & 7))] = f2bf(acc[i][j][r]);
      }
  __syncthreads();
  #pragma unroll
  for (int s = 0; s < 8; ++s) {
    const int g  = s * 256 + tid;   // 16B chunk id
    const int m  = g >> 4;
    const int cr = g & 15;
    *(uint4*)(G + (size_t)(m0 + m) * NW + n0 + cr * 8) =
        *(const uint4*)(lds_a + m * H + ((cr ^ (m & 7)) * 8));
  }
}

// ---------------- edge gather + fused per-graph mean accumulation --------
// h_next[n] = relu(G[n,1024:] + sum_e G[edge_off[e], :128])
// per-node edge range = [row_ptr2[n*8], row_ptr2[n*8+8]) (dst-major sub-bins).
// gmean[g,l,:] += sum over the block's 4 nodes (4 | 1000 -> block never straddles a graph)
__global__ __launch_bounds__(256) void k_gather(
    const unsigned short* __restrict__ G, const int* __restrict__ row_ptr2,
    const int* __restrict__ edge_off, unsigned short* __restrict__ Hnext,
    float* __restrict__ gmean, int layer)
{
  __shared__ float gsum[4][128];
  const int wv   = threadIdx.x >> 6;
  const int node = blockIdx.x * 4 + wv;
  const int lane = threadIdx.x & 63;
  const int half = lane >> 5;
  const int li   = lane & 31;
  const int c0   = li * 4;
  const int beg = row_ptr2[node << 3];
  const int end = row_ptr2[(node << 3) + 8];
  float s0 = 0.f, s1 = 0.f, s2 = 0.f, s3 = 0.f;
  if (half == 0) {   // self term counted once
    uint2 u = *(const uint2*)(G + (size_t)node * NW + 1024 + c0);
    s0 = bf2f((unsigned short)(u.x & 0xffff));
    s1 = bf2f((unsigned short)(u.x >> 16));
    s2 = bf2f((unsigned short)(u.y & 0xffff));
    s3 = bf2f((unsigned short)(u.y >> 16));
  }
#define ACC4(u) { \
    s0 += bf2f((unsigned short)((u).x & 0xffff)); \
    s1 += bf2f((unsigned short)((u).x >> 16));    \
    s2 += bf2f((unsigned short)((u).y & 0xffff)); \
    s3 += bf2f((unsigned short)((u).y >> 16)); }
  int e = beg + half;
  for (; e + 6 < end; e += 8) {   // 4 rows in flight per half = 8 per wave
    int o0 = edge_off[e],     o1 = edge_off[e + 2];
    int o2 = edge_off[e + 4], o3 = edge_off[e + 6];
    uint2 u0 = *(const uint2*)(G + o0 + c0);
    uint2 u1 = *(const uint2*)(G + o1 + c0);
    uint2 u2 = *(const uint2*)(G + o2 + c0);
    uint2 u3 = *(const uint2*)(G + o3 + c0);
    ACC4(u0) ACC4(u1) ACC4(u2) ACC4(u3)
  }
  for (; e < end; e += 2) {
    int o = edge_off[e];
    uint2 u = *(const uint2*)(G + o + c0);
    ACC4(u)
  }
#undef ACC4
  s0 += __shfl_xor(s0, 32);
  s1 += __shfl_xor(s1, 32);
  s2 += __shfl_xor(s2, 32);
  s3 += __shfl_xor(s3, 32);
  const float r0 = fmaxf(s0, 0.f), r1 = fmaxf(s1, 0.f);
  const float r2 = fmaxf(s2, 0.f), r3 = fmaxf(s3, 0.f);
  if (half == 0) {
    uint2 w;
    w.x = (unsigned int)f2bf(r0) | ((unsigned int)f2bf(r1) << 16);
    w.y = (unsigned int)f2bf(r2) | ((unsigned int)f2bf(r3) << 16);
    *(uint2*)(Hnext + (size_t)node * H + c0) = w;
    gsum[wv][c0]     = r0;
    gsum[wv][c0 + 1] = r1;
    gsum[wv][c0 + 2] = r2;
    gsum[wv][c0 + 3] = r3;
  }
  __syncthreads();
  const int t = threadIdx.x;
  if (t < 128) {
    float v = gsum[0][t] + gsum[1][t] + gsum[2][t] + gsum[3][t];
    atomicAdd(&gmean[(size_t)(blockIdx.x / 250) * (NL * H) + layer * H + t], v);
  }
}

// ---------------- readout ----------------
__global__ __launch_bounds__(128) void k_final(
    const unsigned short* __restrict__ hb, const float* __restrict__ gmean,
    const int* __restrict__ gcount,
    const float* __restrict__ rel_tb, const float* __restrict__ Zn,
    const float* __restrict__ projW, const float* __restrict__ projB,
    const float* __restrict__ fcW, const float* __restrict__ fcB,
    const float* __restrict__ repSeq,
    const int* __restrict__ head_ids, const int* __restrict__ tail_ids,
    const int* __restrict__ rel_lab, float* __restrict__ out)
{
  const int b = blockIdx.x;
  const int o = threadIdx.x;   // 128
  __shared__ float gm[384], hf[384], tf[384];
  __shared__ float go[128], ho[128], t_o[128], re[128], rs[128], sv[128];
  __shared__ float lg[128], pr[128], red[128], att[3];

  const int hid = head_ids[b], tlid = tail_ids[b], rl = rel_lab[b];
  const float cinv = 1.f / (float)gcount[b];
  #pragma unroll
  for (int l = 0; l < NL; ++l) {
    gm[l * H + o] = gmean[(size_t)b * (NL * H) + l * H + o] * cinv;
    hf[l * H + o] = bf2f(hb[((size_t)(l + 1) * N_NODES + hid) * H + o]);
    tf[l * H + o] = bf2f(hb[((size_t)(l + 1) * N_NODES + tlid) * H + o]);
  }
  re[o] = rel_tb[rl * H + o];
  rs[o] = repSeq[b * H + o];
  __syncthreads();

  float pb = projB[o];
  float sg = pb, sh = pb, st = pb;
  for (int i = 0; i < NL * H; ++i) {
    float wv = projW[i * H + o];
    sg = fmaf(gm[i], wv, sg);
    sh = fmaf(hf[i], wv, sh);
    st = fmaf(tf[i], wv, st);
  }
  go[o] = (sg > 0.f) ? sg : 0.01f * sg;
  ho[o] = sh;
  t_o[o] = st;
  __syncthreads();

  {
    const int k = o & 63;
    const float* v = (o < 64) ? ho : t_o;
    float s = 0.f;
    for (int i = 0; i < H; ++i) s = fmaf(v[i], Zn[k * H + i], s);
    lg[o] = s;
  }
  __syncthreads();
  if (o < 2) {
    float* l0 = &lg[o * 64];
    float* p0 = &pr[o * 64];
    float mx = l0[0];
    for (int k = 1; k < 64; ++k) mx = fmaxf(mx, l0[k]);
    float sum = 0.f;
    for (int k = 0; k < 64; ++k) { float e = __expf(l0[k] - mx); p0[k] = e; sum += e; }
    float inv = 1.f / sum;
    for (int k = 0; k < 64; ++k) p0[k] *= inv;
  }
  __syncthreads();
  {
    float s1 = 0.f, s2 = 0.f;
    for (int k = 0; k < 64; ++k) {
      float z = Zn[k * H + o];
      s1 = fmaf(pr[k], z, s1);
      s2 = fmaf(pr[64 + k], z, s2);
    }
    s1 = 1.f / (1.f + __expf(-s1));
    s2 = 1.f / (1.f + __expf(-s2));
    sv[o] = s1 * s2;
  }
  __syncthreads();
  if (o == 0) {
    float d0 = 0.f, d1 = 0.f, d2 = 0.f;
    for (int i = 0; i < H; ++i) { d0 += re[i] * go[i]; d1 += re[i] * rs[i]; d2 += re[i] * sv[i]; }
    float mx = fmaxf(d0, fmaxf(d1, d2));
    float e0 = __expf(d0 - mx), e1 = __expf(d1 - mx), e2 = __expf(d2 - mx);
    float inv = 1.f / (e0 + e1 + e2);
    att[0] = e0 * inv; att[1] = e1 * inv; att[2] = e2 * inv;
  }
  __syncthreads();
  float va = att[0] * go[o] + att[1] * rs[o] + att[2] * sv[o];

  float p = 0.f;
  p = fmaf(hf[o],       fcW[o],       p);
  p = fmaf(hf[128 + o], fcW[128 + o], p);
  p = fmaf(hf[256 + o], fcW[256 + o], p);
  p = fmaf(tf[o],       fcW[384 + o], p);
  p = fmaf(tf[128 + o], fcW[512 + o], p);
  p = fmaf(tf[256 + o], fcW[640 + o], p);
  p = fmaf(re[o],       fcW[768 + o], p);
  p = fmaf(va,          fcW[896 + o], p);
  red[o] = p;
  __syncthreads();
  if (o == 0) {
    float s = 0.f;
    for (int i = 0; i < 128; ++i) s += red[i];
    out[b] = s + fcB[0];
  }
}

extern "C" void kernel_launch(void* const* d_in, const int* in_sizes, int n_in,
                              void* d_out, int out_size, void* d_ws, size_t ws_size,
                              hipStream_t stream) {
  const float* x        = (const float*)d_in[0];
  const float* W_rel    = (const float*)d_in[1];
  const float* W_self   = (const float*)d_in[2];
  const float* rel_tb   = (const float*)d_in[3];
  const float* Zn       = (const float*)d_in[4];
  const float* proj_W   = (const float*)d_in[5];
  const float* proj_b   = (const float*)d_in[6];
  const float* fc_W     = (const float*)d_in[7];
  const float* fc_b     = (const float*)d_in[8];
  const float* rep_seq  = (const float*)d_in[9];
  const int* src      = (const int*)d_in[10];
  const int* dst      = (const int*)d_in[11];
  const int* etype    = (const int*)d_in[12];
  const int* graph_id = (const int*)d_in[13];
  const int* head_ids = (const int*)d_in[14];
  const int* tail_ids = (const int*)d_in[15];
  const int* rel_lab  = (const int*)d_in[16];
  float* out = (float*)d_out;

  // workspace carve (~113 MB), all 16B aligned
  char* w = (char*)d_ws;
  unsigned short* G  = (unsigned short*)w; w += (size_t)N_NODES * NW * 2;              // 73.7 MB
  unsigned short* hb = (unsigned short*)w; w += (size_t)(NL + 1) * N_NODES * H * 2;    // 32.8 MB
  unsigned short* Bt = (unsigned short*)w; w += (size_t)NL * NW * H * 2;               // 0.88 MB
  int* row_ptr2 = (int*)w;  w += (size_t)(NBIN2 + 8) * 4;                              // 1.05 MB
  int* cursor   = (int*)w;  w += (size_t)NBIN2 * 4;                                    // 1.05 MB (scan-written)
  int* edge_off = (int*)w;  w += (size_t)NEDGE * 4;
  int* bsum     = (int*)w;  w += (size_t)256 * 4;
  // zero region: cnt | gcount | gmean
  char* z = w;
  int* cnt     = (int*)w;   w += (size_t)NBIN2 * 4;                                    // 1.05 MB
  int* gcount  = (int*)w;   w += (size_t)32 * 4;
  float* gmean = (float*)w; w += (size_t)BSZ * NL * H * 4;
  size_t zbytes = (size_t)(w - z);

  hipMemsetAsync(z, 0, zbytes, stream);
  k_prep <<<7853, 256, 0, stream>>>(x, W_rel, W_self, dst, graph_id, hb, Bt, cnt, gcount);
  k_scanA<<<NBIN2 / 1024, 256, 0, stream>>>(cnt, bsum);
  k_scanC<<<NBIN2 / 1024, 256, 0, stream>>>(cnt, bsum, row_ptr2, cursor);
  k_fill <<<NEDGE / 256, 256, 0, stream>>>(src, dst, etype, cursor, edge_off);

  for (int l = 0; l < NL; ++l) {
    const unsigned short* hp = hb + (size_t)l * N_NODES * H;
    unsigned short* hn = hb + (size_t)(l + 1) * N_NODES * H;
    k_gemm9 <<<dim3(N_NODES / 128, 9), 256, 0, stream>>>(hp, Bt + (size_t)l * NW * H, G);
    k_gather<<<N_NODES / 4, 256, 0, stream>>>(G, row_ptr2, edge_off, hn, gmean, l);
  }
  k_final<<<BSZ, H, 0, stream>>>(hb, gmean, gcount, rel_tb, Zn, proj_W, proj_b, fc_W, fc_b,
                                 rep_seq, head_ids, tail_ids, rel_lab, out);
  (void)in_sizes; (void)n_in; (void)out_size; (void)ws_size;
}